// Round 3
// baseline (319.721 us; speedup 1.0000x reference)
//
#include <hip/hip_runtime.h>

typedef unsigned short u16;
typedef short s16x8 __attribute__((ext_vector_type(8)));
typedef float f32x4 __attribute__((ext_vector_type(4)));

// ---------------- bf16 helpers (RNE) ----------------
static __device__ __forceinline__ u16 f2b(float f) {
  union { float f; unsigned u; } v; v.f = f;
  unsigned r = v.u + 0x7fffu + ((v.u >> 16) & 1u);
  return (u16)(r >> 16);
}
static __device__ __forceinline__ float b2f(u16 u) {
  union { unsigned u; float f; } v; v.u = ((unsigned)u) << 16;
  return v.f;
}

#define MFMA16(a, b, c) __builtin_amdgcn_mfma_f32_16x16x32_bf16((a), (b), (c), 0, 0, 0)

// async global -> LDS, 16B per lane (dest = uniform base + lane*16)
static __device__ __forceinline__ void gload_lds16(const u16* g, u16* l) {
  __builtin_amdgcn_global_load_lds((const __attribute__((address_space(1))) void*)g,
                                   (__attribute__((address_space(3))) void*)l, 16, 0, 0);
}

// ---------------- prep kernels ----------------
__global__ void k_cast_x(const float* __restrict__ src, u16* __restrict__ dst, int n4) {
  int i = blockIdx.x * blockDim.x + threadIdx.x;
  if (i >= n4) return;
  float4 v = ((const float4*)src)[i];
  ushort4 o;
  o.x = f2b(v.x); o.y = f2b(v.y); o.z = f2b(v.z); o.w = f2b(v.w);
  ((ushort4*)dst)[i] = o;
}

// W [1024 u][1024 n] f32 -> Wt [1024 n][1024 u] bf16
__global__ void k_transpose_w(const float* wq, const float* wk, const float* wv, const float* wo,
                              u16* dq, u16* dk, u16* dv, u16* dwo) {
  const float* src; u16* dst;
  int z = blockIdx.z;
  if (z == 0)      { src = wq; dst = dq; }
  else if (z == 1) { src = wk; dst = dk; }
  else if (z == 2) { src = wv; dst = dv; }
  else             { src = wo; dst = dwo; }
  __shared__ float t[32][33];
  int x0 = blockIdx.x * 32, y0 = blockIdx.y * 32;
  int tx = threadIdx.x, ty = threadIdx.y;
#pragma unroll
  for (int k = 0; k < 4; k++) t[ty + 8 * k][tx] = src[(size_t)(y0 + ty + 8 * k) * 1024 + x0 + tx];
  __syncthreads();
#pragma unroll
  for (int k = 0; k < 4; k++) dst[(size_t)(x0 + ty + 8 * k) * 1024 + y0 + tx] = f2b(t[tx][ty + 8 * k]);
}

// ekb: [16][144][64] bf16 (m>=129 zero) ; evt: [16][64][160] bf16 (ev^T per head, m>=129 zero)
__global__ void k_prep_rel(const float* __restrict__ ek, const float* __restrict__ ev,
                           u16* __restrict__ ekb, u16* __restrict__ evt) {
  int i = blockIdx.x * blockDim.x + threadIdx.x;
  if (i < 16 * 144 * 64) {
    int h = i / (144 * 64); int rem = i % (144 * 64); int m = rem / 64; int d = rem % 64;
    ekb[i] = (m < 129) ? f2b(ek[((size_t)h * 129 + m) * 64 + d]) : (u16)0;
  }
  if (i < 16 * 64 * 160) {
    int h = i / (64 * 160); int rem = i % (64 * 160); int d = rem / 160; int mm = rem % 160;
    evt[i] = (mm < 129) ? f2b(ev[((size_t)h * 129 + mm) * 64 + d]) : (u16)0;
  }
}

// ---------------- bf16 MFMA GEMM body: C[4096][1024] = A[4096][1024] * Bt[1024][1024]^T --------
// MODE 0: bf16 -> [B][H][L][D] (Q/K)
// MODE 1: bf16 -> [B][H][D][L] (V^T, via operand-swapped MFMA -> coalesced stores)
// MODE 2: f32 row-major + bias
template <int MODE>
static __device__ __forceinline__ void gemm_body(const u16* __restrict__ A, const u16* __restrict__ Bt,
                                                 void* __restrict__ Cout, const float* __restrict__ bias,
                                                 int bx, int by) {
  __shared__ u16 As[128 * 32];
  __shared__ u16 Bs[128 * 32];
  int tid = threadIdx.x;
  int w = tid >> 6, lane = tid & 63;
  int wrw = w >> 1, wcw = w & 1, lr = lane & 15, lk = lane >> 4;
  int m0 = by * 128, n0 = bx * 128;
  f32x4 acc[4][4] = {};
  int crow = lane >> 2;          // row within 16-row chunk
  int ccol = (lane & 3) * 8;     // u16 col within 32
  const u16* gA = &A [(size_t)(m0 + w * 32 + crow) * 1024 + ccol];
  const u16* gB = &Bt[(size_t)(n0 + w * 32 + crow) * 1024 + ccol];
  u16* lA = &As[w * 32 * 32];
  u16* lB = &Bs[w * 32 * 32];
  for (int k0 = 0; k0 < 1024; k0 += 32) {
    __syncthreads();
    gload_lds16(gA + k0,             lA);
    gload_lds16(gA + k0 + 16 * 1024, lA + 16 * 32);
    gload_lds16(gB + k0,             lB);
    gload_lds16(gB + k0 + 16 * 1024, lB + 16 * 32);
    __syncthreads();
    s16x8 af[4], bfr[4];
#pragma unroll
    for (int mt = 0; mt < 4; mt++) af[mt]  = *(const s16x8*)&As[(wrw * 64 + mt * 16 + lr) * 32 + lk * 8];
#pragma unroll
    for (int nt = 0; nt < 4; nt++) bfr[nt] = *(const s16x8*)&Bs[(wcw * 64 + nt * 16 + lr) * 32 + lk * 8];
    __builtin_amdgcn_s_setprio(1);
#pragma unroll
    for (int mt = 0; mt < 4; mt++)
#pragma unroll
      for (int nt = 0; nt < 4; nt++) {
        if (MODE == 1) acc[mt][nt] = MFMA16(bfr[nt], af[mt], acc[mt][nt]);
        else           acc[mt][nt] = MFMA16(af[mt], bfr[nt], acc[mt][nt]);
      }
    __builtin_amdgcn_s_setprio(0);
  }
#pragma unroll
  for (int mt = 0; mt < 4; mt++)
#pragma unroll
    for (int nt = 0; nt < 4; nt++)
#pragma unroll
      for (int r = 0; r < 4; r++) {
        float v = acc[mt][nt][r];
        if (MODE == 1) {
          // rows = n-dim (u) via lk*4+r ; cols = m-dim (l) via lr -> coalesced along l
          int u = n0 + wcw * 64 + nt * 16 + lk * 4 + r;
          int l = m0 + wrw * 64 + mt * 16 + lr;
          int bb = l >> 10, ll = l & 1023;
          int hh = u >> 6, dd = u & 63;
          ((u16*)Cout)[((size_t)(bb * 16 + hh)) * 65536 + (size_t)dd * 1024 + ll] = f2b(v);
        } else {
          int row = m0 + wrw * 64 + mt * 16 + lk * 4 + r;
          int col = n0 + wcw * 64 + nt * 16 + lr;
          if (MODE == 2) {
            ((float*)Cout)[(size_t)row * 1024 + col] = v + bias[col];
          } else {
            int bb = row >> 10, l = row & 1023;
            int hh = col >> 6, dd = col & 63;
            ((u16*)Cout)[((size_t)(bb * 16 + hh)) * 65536 + (size_t)l * 64 + dd] = f2b(v);
          }
        }
      }
}

__global__ __launch_bounds__(256) void k_gemm_qk(const u16* __restrict__ A,
                                                 const u16* __restrict__ BtQ, const u16* __restrict__ BtK,
                                                 u16* __restrict__ Qo, u16* __restrict__ Ko) {
  const u16* Bt = blockIdx.z ? BtK : BtQ;
  u16* C        = blockIdx.z ? Ko  : Qo;
  gemm_body<0>(A, Bt, C, nullptr, blockIdx.x, blockIdx.y);
}
__global__ __launch_bounds__(256) void k_gemm_v(const u16* __restrict__ A, const u16* __restrict__ Bt,
                                                u16* __restrict__ Vo) {
  gemm_body<1>(A, Bt, Vo, nullptr, blockIdx.x, blockIdx.y);
}
__global__ __launch_bounds__(256) void k_gemm_out(const u16* __restrict__ A, const u16* __restrict__ Bt,
                                                  float* __restrict__ Cout, const float* __restrict__ bias) {
  gemm_body<2>(A, Bt, Cout, bias, blockIdx.x, blockIdx.y);
}

// ---------------- fused relative-position attention ----------------
// One 64-thread wave per 16-row q-tile; swapped QK^T (S[j][i], i=lane&15) makes every
// LDS structure wave-private -> ZERO barriers. No max-subtraction (logits O(1); fmin(80) guard).
// LDS 15.8 KB/block -> ~9 blocks/CU.
//   qm_s   @ 0     : [16][136] bf16 = 4352
//   P_s    @ 4352  : [16][136] bf16 = 4352
//   wrb    @ 8704  : [16][168] bf16 = 5376   (buckets 0..128 used; 129..159 stay zero for K-pad)
//   mask_s @ 14080 : [1024]    bf16 = 2048   (additive mask, pmask*-1e9)
__global__ __launch_bounds__(64) void k_attn(const u16* __restrict__ Qg, const u16* __restrict__ Kg,
                                             const u16* __restrict__ Vt, const u16* __restrict__ ekb,
                                             const u16* __restrict__ evt, const float* __restrict__ pmask,
                                             u16* __restrict__ Og) {
  __shared__ alignas(16) char smem[16128];
  u16* qm_s   = (u16*)smem;
  u16* P_s    = (u16*)(smem + 4352);
  u16* wrb    = (u16*)(smem + 8704);
  u16* mask_s = (u16*)(smem + 14080);

  int lane = threadIdx.x;
  int lr = lane & 15, lk = lane >> 4;
  // XCD-bijective swizzle: blocks sharing (b,h) land on one XCD (K/V L2 locality)
  int wg = (blockIdx.x & 7) * 512 + (blockIdx.x >> 3);
  int bh = wg >> 6, it = wg & 63;
  int b = bh >> 4, h = bh & 15;
  int i0 = it * 16;

  // stage additive mask (bf16) for this batch row
  {
    const float4* pm4 = (const float4*)(pmask + (size_t)b * 1024);
#pragma unroll
    for (int t = 0; t < 4; t++) {
      float4 v = pm4[lane * 4 + t];
      unsigned w0 = (unsigned)f2b(v.x * -1e9f) | ((unsigned)f2b(v.y * -1e9f) << 16);
      unsigned w1 = (unsigned)f2b(v.z * -1e9f) | ((unsigned)f2b(v.w * -1e9f) << 16);
      ((unsigned*)mask_s)[lane * 8 + t * 2]     = w0;
      ((unsigned*)mask_s)[lane * 8 + t * 2 + 1] = w1;
    }
  }
  // zero wrb
  for (int t = lane; t < 1344; t += 64) ((unsigned*)wrb)[t] = 0u;

  // Q fragments
  const u16* qp = &Qg[((size_t)bh * 1024 + i0 + lr) * 64 + lk * 8];
  s16x8 aq0 = *(const s16x8*)qp;
  s16x8 aq1 = *(const s16x8*)(qp + 32);

  // qm[i][m] = q_i . ek[h][m] ; rows via lk*4+r, cols via lr
#pragma unroll
  for (int nt = 0; nt < 9; nt++) {
    f32x4 c = {};
    const u16* ekp = &ekb[((size_t)h * 144 + nt * 16 + lr) * 64 + lk * 8];
    c = MFMA16(aq0, *(const s16x8*)ekp, c);
    c = MFMA16(aq1, *(const s16x8*)(ekp + 32), c);
    int mcol = nt * 16 + lr;
    if (mcol < 129) {
#pragma unroll
      for (int r = 0; r < 4; r++) qm_s[(lk * 4 + r) * 136 + mcol] = f2b(c[r]);
    }
  }

  float ssum = 0.f, lsum = 0.f, rsum = 0.f;
  f32x4 oacc[4] = {};
  const int ig = i0 + lr;   // this lane's query row (swapped layout: col = i = lr)

  for (int jt = 0; jt < 8; jt++) {
    int j0 = jt * 128;
    float p[8][4];
    const u16* kbase = &Kg[((size_t)bh * 1024 + j0 + lr) * 64 + lk * 8];
#pragma unroll
    for (int nt = 0; nt < 8; nt++) {
      f32x4 c = {};
      const u16* kp = kbase + nt * 16 * 64;
      c = MFMA16(*(const s16x8*)kp, aq0, c);          // swapped: rows=j, cols=i
      c = MFMA16(*(const s16x8*)(kp + 32), aq1, c);
#pragma unroll
      for (int r = 0; r < 4; r++) {
        int j = j0 + nt * 16 + lk * 4 + r;
        int dl = j - ig;
        dl = dl < -64 ? -64 : (dl > 64 ? 64 : dl);
        float qmv = b2f(qm_s[lr * 136 + dl + 64]);
        float madd = b2f(mask_s[j]);
        float sval = fminf((c[r] + qmv) * 0.125f + madd, 80.f);
        float pv = __expf(sval);
        p[nt][r] = pv;
        ssum += pv;
      }
    }
    // pack P~ to LDS A-fragment layout: P[i=lr][j]
#pragma unroll
    for (int nt = 0; nt < 8; nt++) {
      unsigned lo, hi;
      asm("v_cvt_pk_bf16_f32 %0, %1, %2" : "=v"(lo) : "v"(p[nt][0]), "v"(p[nt][1]));
      asm("v_cvt_pk_bf16_f32 %0, %1, %2" : "=v"(hi) : "v"(p[nt][2]), "v"(p[nt][3]));
      uint2 pk; pk.x = lo; pk.y = hi;
      *(uint2*)&P_s[lr * 136 + nt * 16 + lk * 4] = pk;
    }
    // PV: oacc[i][d] += P~ . V
    __builtin_amdgcn_s_setprio(1);
    {
      s16x8 ap[4];
#pragma unroll
      for (int kk = 0; kk < 4; kk++) ap[kk] = *(const s16x8*)&P_s[lr * 136 + kk * 32 + lk * 8];
      const u16* vbase = &Vt[((size_t)bh * 64 + lr) * 1024 + j0 + lk * 8];
#pragma unroll
      for (int nt = 0; nt < 4; nt++) {
        const u16* vp = vbase + nt * 16 * 1024;
#pragma unroll
        for (int kk = 0; kk < 4; kk++)
          oacc[nt] = MFMA16(ap[kk], *(const s16x8*)(vp + kk * 32), oacc[nt]);
      }
    }
    __builtin_amdgcn_s_setprio(0);
    // wr scatter from registers: this lane owns row ig
    {
      int jmin = j0 + lk * 4;
      int jmax = j0 + 112 + lk * 4 + 3;
      if (jmax <= ig - 64) {
        float s = 0.f;
#pragma unroll
        for (int nt = 0; nt < 8; nt++) s += (p[nt][0] + p[nt][1]) + (p[nt][2] + p[nt][3]);
        lsum += s;
      } else if (jmin >= ig + 64) {
        float s = 0.f;
#pragma unroll
        for (int nt = 0; nt < 8; nt++) s += (p[nt][0] + p[nt][1]) + (p[nt][2] + p[nt][3]);
        rsum += s;
      } else {
#pragma unroll
        for (int nt = 0; nt < 8; nt++)
#pragma unroll
          for (int r = 0; r < 4; r++) {
            int dl = j0 + nt * 16 + lk * 4 + r - ig;
            if (dl <= -64) lsum += p[nt][r];
            else if (dl >= 64) rsum += p[nt][r];
            else wrb[lr * 168 + dl + 64] = f2b(p[nt][r]);
          }
      }
    }
  }

  // reduce across the 4 lanes sharing lr (lanes lr, lr+16, lr+32, lr+48)
  lsum += __shfl_xor(lsum, 16); lsum += __shfl_xor(lsum, 32);
  rsum += __shfl_xor(rsum, 16); rsum += __shfl_xor(rsum, 32);
  ssum += __shfl_xor(ssum, 16); ssum += __shfl_xor(ssum, 32);
  if (lk == 0) {
    wrb[lr * 168]       = f2b(lsum);
    wrb[lr * 168 + 128] = f2b(rsum);
  }

  // oacc += wr . Ev
  __builtin_amdgcn_s_setprio(1);
  {
    s16x8 aw[5];
#pragma unroll
    for (int kk = 0; kk < 5; kk++) aw[kk] = *(const s16x8*)&wrb[lr * 168 + kk * 32 + lk * 8];
    const u16* ebase = &evt[((size_t)h * 64 + lr) * 160 + lk * 8];
#pragma unroll
    for (int nt = 0; nt < 4; nt++) {
      const u16* ep = ebase + nt * 16 * 160;
#pragma unroll
      for (int kk = 0; kk < 5; kk++)
        oacc[nt] = MFMA16(aw[kk], *(const s16x8*)(ep + kk * 32), oacc[nt]);
    }
  }
  __builtin_amdgcn_s_setprio(0);

  // normalize + write O[(b,l)][(h,d)]
  float rden[4];
#pragma unroll
  for (int r = 0; r < 4; r++) rden[r] = 1.0f / __shfl(ssum, lk * 4 + r);
  u16* obase = &Og[((size_t)(b * 1024 + i0)) * 1024 + h * 64];
#pragma unroll
  for (int nt = 0; nt < 4; nt++)
#pragma unroll
    for (int r = 0; r < 4; r++) {
      int il = lk * 4 + r;
      obase[(size_t)il * 1024 + nt * 16 + lr] = f2b(oacc[nt][r] * rden[r]);
    }
}

// ---------------- launch ----------------
#define OFF_XB   0u
#define OFF_WQT  8388608u
#define OFF_WKT  10485760u
#define OFF_WVT  12582912u
#define OFF_WOT  14680064u
#define OFF_Q    16777216u
#define OFF_K    25165824u
#define OFF_VT   33554432u
#define OFF_O    41943040u
#define OFF_EKB  50331648u
#define OFF_EVT  50626560u

extern "C" void kernel_launch(void* const* d_in, const int* in_sizes, int n_in,
                              void* d_out, int out_size, void* d_ws, size_t ws_size,
                              hipStream_t stream) {
  const float* x  = (const float*)d_in[0];
  const float* pm = (const float*)d_in[1];
  const float* wq = (const float*)d_in[2];
  const float* wk = (const float*)d_in[3];
  const float* wv = (const float*)d_in[4];
  const float* wo = (const float*)d_in[5];
  const float* bo = (const float*)d_in[6];
  const float* ek = (const float*)d_in[7];
  const float* ev = (const float*)d_in[8];
  char* ws = (char*)d_ws;
  u16* Xb  = (u16*)(ws + OFF_XB);
  u16* Wqt = (u16*)(ws + OFF_WQT);
  u16* Wkt = (u16*)(ws + OFF_WKT);
  u16* Wvt = (u16*)(ws + OFF_WVT);
  u16* Wot = (u16*)(ws + OFF_WOT);
  u16* Qg  = (u16*)(ws + OFF_Q);
  u16* Kg  = (u16*)(ws + OFF_K);
  u16* Vtg = (u16*)(ws + OFF_VT);
  u16* Og  = (u16*)(ws + OFF_O);
  u16* EKB = (u16*)(ws + OFF_EKB);
  u16* EVT = (u16*)(ws + OFF_EVT);

  k_cast_x<<<4096, 256, 0, stream>>>(x, Xb, 1048576);
  {
    dim3 tb(32, 8), tg(32, 32, 4);
    k_transpose_w<<<tg, tb, 0, stream>>>(wq, wk, wv, wo, Wqt, Wkt, Wvt, Wot);
  }
  k_prep_rel<<<640, 256, 0, stream>>>(ek, ev, EKB, EVT);
  {
    dim3 gqk(8, 32, 2);
    k_gemm_qk<<<gqk, 256, 0, stream>>>(Xb, Wqt, Wkt, Qg, Kg);
    dim3 gv(8, 32);
    k_gemm_v<<<gv, 256, 0, stream>>>(Xb, Wvt, Vtg);
    k_attn<<<4096, 64, 0, stream>>>(Qg, Kg, Vtg, EKB, EVT, pm, Og);
    dim3 go(8, 32);
    k_gemm_out<<<go, 256, 0, stream>>>(Og, Wot, (float*)d_out, bo);
  }
}